// Round 4
// baseline (198.886 us; speedup 1.0000x reference)
//
#include <hip/hip_runtime.h>
#include <hip/hip_bf16.h>

typedef unsigned short u16;
typedef __bf16 bf16x8 __attribute__((ext_vector_type(8)));
typedef float f32x4 __attribute__((ext_vector_type(4)));

#define T_TOTAL 8192
#define F_DIM   2048
#define O_DIM   2048
#define E_NUM   8

__device__ __forceinline__ u16 f2bf(float f) {
  return __builtin_bit_cast(u16, (__bf16)f);  // RTNE
}
__device__ __forceinline__ unsigned pack2(float a, float b) {
  return (unsigned)f2bf(a) | ((unsigned)f2bf(b) << 16);
}
__device__ __forceinline__ bf16x8 packbf8(f32x4 v0, f32x4 v1) {
  uint4 hv;
  hv.x = pack2(v0[0], v0[1]); hv.y = pack2(v0[2], v0[3]);
  hv.z = pack2(v1[0], v1[1]); hv.w = pack2(v1[2], v1[3]);
  return __builtin_bit_cast(bf16x8, hv);
}

// ---------------------------------------------------------------------------
// prep: build fragment-packed bf16 copies of A and B so MFMA operand
// fragments are contiguous 1KB-per-wave-instruction loads (L2-resident).
//   Apack chunk c = ((kt*8 + s)*4 + kk)*64 + lane, elem j:
//       A[er = s*16 + (lane&15)][k = kt*128 + kk*32 + (lane>>4)*8 + j]
//   Bpack chunk c = ((ot*8 + s)*4 + kk)*64 + lane, elem j:
//       B_T[o = ot*128 + s*16 + (lane&15)][er = kk*32 + (lane>>4)*8 + j]
// ---------------------------------------------------------------------------
__global__ __launch_bounds__(256) void prep_kernel(
    const float* __restrict__ A, const float* __restrict__ Bst,
    u16* __restrict__ Apack, u16* __restrict__ Bpack) {
  const int i  = blockIdx.x * 256 + threadIdx.x;   // 0 .. 262143
  const int j  = i & 7;
  const int l  = (i >> 3) & 63;
  const int kk = (i >> 9) & 3;
  const int s  = (i >> 11) & 7;
  const int t  = i >> 14;                          // kt or ot, 0..15
  const int lm = l & 15, g = l >> 4;
  {
    const int er = s * 16 + lm;
    const int k  = t * 128 + kk * 32 + g * 8 + j;
    Apack[i] = f2bf(A[er * F_DIM + k]);
  }
  {
    const int o  = t * 128 + s * 16 + lm;
    const int er = kk * 32 + g * 8 + j;
    Bpack[i] = f2bf(Bst[(er >> 4) * (O_DIM * 16) + o * 16 + (er & 15)]);
  }
}

// ---------------------------------------------------------------------------
// fused: 16 tokens/block, 256 threads (4 waves), 512 blocks (2/CU).
// Phase 1 (barrier-free): sim (fp32 VALU) + z_all (MFMA, operands direct
//   from global: x rows -> cvt, Apack fragments from L2).
// Softmax handoff: 3 barriers total.
// Phase 2 (barrier-free): out = zc @ B, zc frags hoisted to regs,
//   Bpack fragments from L2, streaming f32 stores.
// ---------------------------------------------------------------------------
__global__ __launch_bounds__(256, 2) void fused_kernel(
    const float* __restrict__ x, const float* __restrict__ protos,
    const float* __restrict__ scales, const u16* __restrict__ Apack,
    const u16* __restrict__ Bpack, float* __restrict__ out) {
  __shared__ float sim_lds[16][8];
  __shared__ float w_lds[16][8];
  __shared__ u16  zc_lds[16 * 128];

  const int tid  = threadIdx.x;
  const int t0   = blockIdx.x * 16;
  const int row  = tid >> 4;          // 0..15 token (sim role)
  const int seg  = tid & 15;          // 0..15 k-segment of 8 floats
  const int lane = tid & 63;
  const int w    = tid >> 6;          // 0..3 wave
  const int g    = lane >> 4;
  const int lm   = lane & 15;

  float sacc[E_NUM];
#pragma unroll
  for (int e = 0; e < E_NUM; ++e) sacc[e] = 0.f;
  const f32x4 z4 = {0.f, 0.f, 0.f, 0.f};
  f32x4 acc1[2];
  acc1[0] = z4; acc1[1] = z4;

  const float* xs_ptr = x + (size_t)(t0 + row) * F_DIM + seg * 8;  // sim view
  const float* xf_ptr = x + (size_t)(t0 + lm) * F_DIM;             // frag view

#pragma unroll 2
  for (int kt = 0; kt < 16; ++kt) {
    const int kb = kt * 128;
    // ---- fp32 sim partials ----
    f32x4 a0 = *reinterpret_cast<const f32x4*>(xs_ptr + kb);
    f32x4 a1 = *reinterpret_cast<const f32x4*>(xs_ptr + kb + 4);
#pragma unroll
    for (int e = 0; e < E_NUM; ++e) {
      const float* pp = protos + e * F_DIM + kb + seg * 8;
      f32x4 p0 = *reinterpret_cast<const f32x4*>(pp);
      f32x4 p1 = *reinterpret_cast<const f32x4*>(pp + 4);
      sacc[e] += a0[0]*p0[0] + a0[1]*p0[1] + a0[2]*p0[2] + a0[3]*p0[3]
               + a1[0]*p1[0] + a1[1]*p1[1] + a1[2]*p1[2] + a1[3]*p1[3];
    }
    // ---- MFMA: z strip er in [w*32, w*32+32) ----
#pragma unroll
    for (int kk = 0; kk < 4; ++kk) {
      const float* xf = xf_ptr + kb + kk * 32 + g * 8;
      f32x4 v0 = *reinterpret_cast<const f32x4*>(xf);
      f32x4 v1 = *reinterpret_cast<const f32x4*>(xf + 4);
      bf16x8 av = packbf8(v0, v1);
#pragma unroll
      for (int n = 0; n < 2; ++n) {
        bf16x8 bv = *reinterpret_cast<const bf16x8*>(
            Apack + ((((size_t)kt * 8 + (w * 2 + n)) * 4 + kk) * 64 + lane) * 8);
        acc1[n] = __builtin_amdgcn_mfma_f32_16x16x32_bf16(av, bv, acc1[n], 0, 0, 0);
      }
    }
  }

  // ---- sim reduction over 16 seg-lanes (within wave) ----
#pragma unroll
  for (int s = 1; s < 16; s <<= 1)
#pragma unroll
    for (int e = 0; e < E_NUM; ++e) sacc[e] += __shfl_xor(sacc[e], s);
  if (seg < E_NUM) sim_lds[row][seg] = sacc[seg];
  __syncthreads();

  // ---- top-2 + softmax + scale ----
  if (tid < 16) {
    float sv[E_NUM];
#pragma unroll
    for (int e = 0; e < E_NUM; ++e) sv[e] = fabsf(sim_lds[tid][e]);
    int e0 = 0; float b0 = sv[0];
#pragma unroll
    for (int e = 1; e < E_NUM; ++e) if (sv[e] > b0) { b0 = sv[e]; e0 = e; }
    int e1 = -1; float b1 = -3.0e38f;
#pragma unroll
    for (int e = 0; e < E_NUM; ++e) if (e != e0 && sv[e] > b1) { b1 = sv[e]; e1 = e; }
    const float d  = __expf(b1 - b0);   // <= 1, stable
    const float c0 = 1.f / (1.f + d);
    const float c1 = d * c0;
#pragma unroll
    for (int e = 0; e < E_NUM; ++e) w_lds[tid][e] = 0.f;
    w_lds[tid][e0] = c0 * scales[e0];
    w_lds[tid][e1] = c1 * scales[e1];
  }
  __syncthreads();

  // ---- zc = w * z_all -> LDS (XOR-swizzled rows) ----
#pragma unroll
  for (int n = 0; n < 2; ++n) {
    const int s2 = w * 2 + n;
#pragma unroll
    for (int i = 0; i < 4; ++i) {
      const int t = g * 4 + i;
      zc_lds[t * 128 + ((s2 * 16 + lm) ^ ((t & 7) << 3))] =
          f2bf(acc1[n][i] * w_lds[t][s2]);
    }
  }
  __syncthreads();

  // ---- phase 2: out[16 x 2048] = zc @ B ----
  bf16x8 av2[4];
#pragma unroll
  for (int kk = 0; kk < 4; ++kk)
    av2[kk] = *reinterpret_cast<const bf16x8*>(
        &zc_lds[lm * 128 + ((kk * 32 + g * 8) ^ ((lm & 7) << 3))]);

#pragma unroll 2
  for (int ot = 0; ot < 16; ++ot) {
    f32x4 acc2[2];
    acc2[0] = z4; acc2[1] = z4;
#pragma unroll
    for (int kk = 0; kk < 4; ++kk) {
#pragma unroll
      for (int n = 0; n < 2; ++n) {
        bf16x8 bv = *reinterpret_cast<const bf16x8*>(
            Bpack + ((((size_t)ot * 8 + (w * 2 + n)) * 4 + kk) * 64 + lane) * 8);
        acc2[n] = __builtin_amdgcn_mfma_f32_16x16x32_bf16(av2[kk], bv, acc2[n], 0, 0, 0);
      }
    }
#pragma unroll
    for (int n = 0; n < 2; ++n) {
      const int o = ot * 128 + (w * 2 + n) * 16 + lm;
#pragma unroll
      for (int i = 0; i < 4; ++i)
        out[(size_t)(t0 + g * 4 + i) * O_DIM + o] = acc2[n][i];
    }
  }
}

// ---------------------------------------------------------------------------
extern "C" void kernel_launch(void* const* d_in, const int* in_sizes, int n_in,
                              void* d_out, int out_size, void* d_ws, size_t ws_size,
                              hipStream_t stream) {
  const float* x      = (const float*)d_in[0];
  const float* protos = (const float*)d_in[1];
  const float* A      = (const float*)d_in[2];
  const float* Bst    = (const float*)d_in[3];
  const float* scales = (const float*)d_in[4];
  // d_in[5] = top_k (always 2)

  u16* Apack = (u16*)d_ws;                       // 128*2048 bf16, frag-packed
  u16* Bpack = Apack + (size_t)128 * F_DIM;      // 2048*128 bf16, frag-packed
  float* out = (float*)d_out;

  prep_kernel<<<(128 * F_DIM) / 256, 256, 0, stream>>>(A, Bst, Apack, Bpack);
  fused_kernel<<<T_TOTAL / 16, 256, 0, stream>>>(x, protos, scales, Apack, Bpack, out);
}

// Round 5
// 187.841 us; speedup vs baseline: 1.0588x; 1.0588x over previous
//
#include <hip/hip_runtime.h>
#include <hip/hip_bf16.h>

typedef unsigned short u16;
typedef __bf16 bf16x8 __attribute__((ext_vector_type(8)));
typedef float f32x4 __attribute__((ext_vector_type(4)));

#define T_TOTAL 8192
#define F_DIM   2048
#define O_DIM   2048
#define E_NUM   8

__device__ __forceinline__ u16 f2bf(float f) {
  return __builtin_bit_cast(u16, (__bf16)f);  // RTNE
}
__device__ __forceinline__ unsigned pack2(float a, float b) {
  return (unsigned)f2bf(a) | ((unsigned)f2bf(b) << 16);
}
__device__ __forceinline__ bf16x8 packbf8(f32x4 v0, f32x4 v1) {
  uint4 hv;
  hv.x = pack2(v0[0], v0[1]); hv.y = pack2(v0[2], v0[3]);
  hv.z = pack2(v1[0], v1[1]); hv.w = pack2(v1[2], v1[3]);
  return __builtin_bit_cast(bf16x8, hv);
}

// ---------------------------------------------------------------------------
// prep: fragment-packed bf16 copies of A and B (verified in Round 4).
//   Apack chunk c = ((kt*8 + s)*4 + kk)*64 + lane, elem j:
//       A[er = s*16 + (lane&15)][k = kt*128 + kk*32 + (lane>>4)*8 + j]
//   Bpack chunk c = ((ot*8 + s)*4 + kk)*64 + lane, elem j:
//       B_T[o = ot*128 + s*16 + (lane&15)][er = kk*32 + (lane>>4)*8 + j]
// ---------------------------------------------------------------------------
__global__ __launch_bounds__(256) void prep_kernel(
    const float* __restrict__ A, const float* __restrict__ Bst,
    u16* __restrict__ Apack, u16* __restrict__ Bpack) {
  const int i  = blockIdx.x * 256 + threadIdx.x;   // 0 .. 262143
  const int j  = i & 7;
  const int l  = (i >> 3) & 63;
  const int kk = (i >> 9) & 3;
  const int s  = (i >> 11) & 7;
  const int t  = i >> 14;                          // kt or ot, 0..15
  const int lm = l & 15, g = l >> 4;
  {
    const int er = s * 16 + lm;
    const int k  = t * 128 + kk * 32 + g * 8 + j;
    Apack[i] = f2bf(A[er * F_DIM + k]);
  }
  {
    const int o  = t * 128 + s * 16 + lm;
    const int er = kk * 32 + g * 8 + j;
    Bpack[i] = f2bf(Bst[(er >> 4) * (O_DIM * 16) + o * 16 + (er & 15)]);
  }
}

// ---------------------------------------------------------------------------
// k1: 16 tokens/block, 256 threads (4 waves), 512 blocks.
// fp32 sim + bf16 MFMA z, all operands in registers with distance-2
// software-pipelined prefetch (no per-step barriers). Outputs zc in the
// frag-packed global layout: zcp chunk ((tb*4 + kk)*64 + lane)*8.
// ---------------------------------------------------------------------------
__global__ __launch_bounds__(256, 2) void k1_kernel(
    const float* __restrict__ x, const float* __restrict__ protos,
    const float* __restrict__ scales, const u16* __restrict__ Apack,
    u16* __restrict__ zcp) {
  __shared__ float sim_lds[16][8];
  __shared__ float w_lds[16][8];
  __shared__ u16  zc_lds[16 * 128];

  const int tid  = threadIdx.x;
  const int t0   = blockIdx.x * 16;
  const int row  = tid >> 4;          // 0..15 token (sim role)
  const int seg  = tid & 15;          // 0..15 k-segment of 8 floats
  const int lane = tid & 63;
  const int w    = tid >> 6;          // 0..3 wave
  const int g    = lane >> 4;
  const int lm   = lane & 15;
  const int w2   = w * 2;

  const float* xs_ptr = x + (size_t)(t0 + row) * F_DIM + seg * 8;
  const float* xf_ptr = x + (size_t)(t0 + lm) * F_DIM + g * 8;
  const u16*   apl    = Apack + lane * 8;

  float sacc[E_NUM];
#pragma unroll
  for (int e = 0; e < E_NUM; ++e) sacc[e] = 0.f;
  const f32x4 z4 = {0.f, 0.f, 0.f, 0.f};
  f32x4 acc1[2];
  acc1[0] = z4; acc1[1] = z4;

#define LOADX(XF, XS0, XS1, kt) do {                                          \
    XS0 = *reinterpret_cast<const f32x4*>(xs_ptr + (kt) * 128);               \
    XS1 = *reinterpret_cast<const f32x4*>(xs_ptr + (kt) * 128 + 4);           \
    _Pragma("unroll")                                                         \
    for (int kk = 0; kk < 4; ++kk) {                                          \
      XF[kk * 2]     = *reinterpret_cast<const f32x4*>(                       \
          xf_ptr + (kt) * 128 + kk * 32);                                     \
      XF[kk * 2 + 1] = *reinterpret_cast<const f32x4*>(                       \
          xf_ptr + (kt) * 128 + kk * 32 + 4);                                 \
    } } while (0)

#define LOADA(AF, kt) do {                                                    \
    _Pragma("unroll")                                                         \
    for (int n = 0; n < 2; ++n)                                               \
      _Pragma("unroll")                                                       \
      for (int kk = 0; kk < 4; ++kk)                                          \
        AF[n * 4 + kk] = *reinterpret_cast<const bf16x8*>(                    \
            apl + (size_t)(((kt) * 8 + w2 + n) * 4 + kk) * 512);              \
    } while (0)

#define STEP(XF, XS0, XS1, AF, kt) do {                                       \
    _Pragma("unroll")                                                         \
    for (int e = 0; e < E_NUM; ++e) {                                         \
      const float* pp = protos + e * F_DIM + (kt) * 128 + seg * 8;            \
      f32x4 p0 = *reinterpret_cast<const f32x4*>(pp);                         \
      f32x4 p1 = *reinterpret_cast<const f32x4*>(pp + 4);                     \
      sacc[e] += XS0[0]*p0[0] + XS0[1]*p0[1] + XS0[2]*p0[2] + XS0[3]*p0[3]    \
               + XS1[0]*p1[0] + XS1[1]*p1[1] + XS1[2]*p1[2] + XS1[3]*p1[3];   \
    }                                                                         \
    _Pragma("unroll")                                                         \
    for (int kk = 0; kk < 4; ++kk) {                                          \
      bf16x8 av = packbf8(XF[kk * 2], XF[kk * 2 + 1]);                        \
      acc1[0] = __builtin_amdgcn_mfma_f32_16x16x32_bf16(av, AF[kk],           \
                                                        acc1[0], 0, 0, 0);    \
      acc1[1] = __builtin_amdgcn_mfma_f32_16x16x32_bf16(av, AF[4 + kk],       \
                                                        acc1[1], 0, 0, 0);    \
    } } while (0)

  f32x4  xfA[8], xfB[8];
  f32x4  xsA0, xsA1, xsB0, xsB1;
  bf16x8 afA[8], afB[8];

  LOADX(xfA, xsA0, xsA1, 0); LOADA(afA, 0);
  LOADX(xfB, xsB0, xsB1, 1); LOADA(afB, 1);

#pragma unroll
  for (int ktt = 0; ktt < 7; ++ktt) {
    STEP(xfA, xsA0, xsA1, afA, 2 * ktt);
    LOADX(xfA, xsA0, xsA1, 2 * ktt + 2); LOADA(afA, 2 * ktt + 2);
    STEP(xfB, xsB0, xsB1, afB, 2 * ktt + 1);
    LOADX(xfB, xsB0, xsB1, 2 * ktt + 3); LOADA(afB, 2 * ktt + 3);
  }
  STEP(xfA, xsA0, xsA1, afA, 14);
  STEP(xfB, xsB0, xsB1, afB, 15);

  // ---- sim reduction over 16 seg-lanes (within wave) ----
#pragma unroll
  for (int s = 1; s < 16; s <<= 1)
#pragma unroll
    for (int e = 0; e < E_NUM; ++e) sacc[e] += __shfl_xor(sacc[e], s);
  if (seg < E_NUM) sim_lds[row][seg] = sacc[seg];
  __syncthreads();

  // ---- top-2 + softmax + scale ----
  if (tid < 16) {
    float sv[E_NUM];
#pragma unroll
    for (int e = 0; e < E_NUM; ++e) sv[e] = fabsf(sim_lds[tid][e]);
    int e0 = 0; float b0 = sv[0];
#pragma unroll
    for (int e = 1; e < E_NUM; ++e) if (sv[e] > b0) { b0 = sv[e]; e0 = e; }
    int e1 = -1; float b1 = -3.0e38f;
#pragma unroll
    for (int e = 0; e < E_NUM; ++e) if (e != e0 && sv[e] > b1) { b1 = sv[e]; e1 = e; }
    const float d  = __expf(b1 - b0);   // <= 1, stable
    const float c0 = 1.f / (1.f + d);
    const float c1 = d * c0;
#pragma unroll
    for (int e = 0; e < E_NUM; ++e) w_lds[tid][e] = 0.f;
    w_lds[tid][e0] = c0 * scales[e0];
    w_lds[tid][e1] = c1 * scales[e1];
  }
  __syncthreads();

  // ---- zc = w * z -> LDS (XOR-swizzled rows) ----
#pragma unroll
  for (int n = 0; n < 2; ++n) {
    const int s2 = w2 + n;
#pragma unroll
    for (int i = 0; i < 4; ++i) {
      const int t = g * 4 + i;
      zc_lds[t * 128 + ((s2 * 16 + lm) ^ ((t & 7) << 3))] =
          f2bf(acc1[n][i] * w_lds[t][s2]);
    }
  }
  __syncthreads();

  // ---- coalesced frag-packed zc store: chunk ((tb*4+kk)*64+l)*8 ----
  {
    const int kks = tid >> 6, l = tid & 63;
    const int t = l & 15, erb = kks * 32 + (l >> 4) * 8;
    uint4 v = *reinterpret_cast<const uint4*>(
        &zc_lds[t * 128 + (erb ^ ((t & 7) << 3))]);
    *reinterpret_cast<uint4*>(
        zcp + ((size_t)(blockIdx.x * 4 + kks) * 64 + l) * 8) = v;
  }
}

// ---------------------------------------------------------------------------
// k2: out[16t x 512o] per block; 2048 blocks, 256 threads, no LDS, no
// barriers. zc frags via contiguous packed loads; B frags prefetched
// distance-2; streaming stores (4 x 64B segments per wave-store).
// ---------------------------------------------------------------------------
__global__ __launch_bounds__(256, 4) void k2_kernel(
    const u16* __restrict__ zcp, const u16* __restrict__ Bpack,
    float* __restrict__ out) {
  const int tid  = threadIdx.x;
  const int lane = tid & 63;
  const int w    = tid >> 6;
  const int g    = lane >> 4;
  const int lm   = lane & 15;
  const int w2   = w * 2;
  const int tb   = blockIdx.x;
  const int oc   = blockIdx.y;
  const int t0   = tb * 16;
  const u16* bpl = Bpack + lane * 8;
  const f32x4 z4 = {0.f, 0.f, 0.f, 0.f};

  bf16x8 av2[4];
#pragma unroll
  for (int kk = 0; kk < 4; ++kk)
    av2[kk] = *reinterpret_cast<const bf16x8*>(
        zcp + ((size_t)(tb * 4 + kk) * 64 + lane) * 8);

#define LOADB(BF, ot) do {                                                    \
    _Pragma("unroll")                                                         \
    for (int n = 0; n < 2; ++n)                                               \
      _Pragma("unroll")                                                       \
      for (int kk = 0; kk < 4; ++kk)                                          \
        BF[n * 4 + kk] = *reinterpret_cast<const bf16x8*>(                    \
            bpl + (size_t)(((oc * 4 + (ot)) * 8 + w2 + n) * 4 + kk) * 512);   \
    } while (0)

#define STEP2(BF, ot) do {                                                    \
    f32x4 a0 = z4, a1 = z4;                                                   \
    _Pragma("unroll")                                                         \
    for (int kk = 0; kk < 4; ++kk) {                                          \
      a0 = __builtin_amdgcn_mfma_f32_16x16x32_bf16(av2[kk], BF[kk],           \
                                                   a0, 0, 0, 0);              \
      a1 = __builtin_amdgcn_mfma_f32_16x16x32_bf16(av2[kk], BF[4 + kk],       \
                                                   a1, 0, 0, 0);              \
    }                                                                         \
    const int ob = (oc * 4 + (ot)) * 128;                                     \
    _Pragma("unroll")                                                         \
    for (int i = 0; i < 4; ++i) {                                             \
      out[(size_t)(t0 + g * 4 + i) * O_DIM + ob + w2 * 16 + lm]       = a0[i];\
      out[(size_t)(t0 + g * 4 + i) * O_DIM + ob + (w2 + 1) * 16 + lm] = a1[i];\
    } } while (0)

  bf16x8 bfA[8], bfB[8];
  LOADB(bfA, 0); LOADB(bfB, 1);
  STEP2(bfA, 0); LOADB(bfA, 2);
  STEP2(bfB, 1); LOADB(bfB, 3);
  STEP2(bfA, 2);
  STEP2(bfB, 3);
}

// ---------------------------------------------------------------------------
extern "C" void kernel_launch(void* const* d_in, const int* in_sizes, int n_in,
                              void* d_out, int out_size, void* d_ws, size_t ws_size,
                              hipStream_t stream) {
  const float* x      = (const float*)d_in[0];
  const float* protos = (const float*)d_in[1];
  const float* A      = (const float*)d_in[2];
  const float* Bst    = (const float*)d_in[3];
  const float* scales = (const float*)d_in[4];
  // d_in[5] = top_k (always 2)

  u16* Apack = (u16*)d_ws;                        // 128*2048 bf16 frag-packed
  u16* Bpack = Apack + (size_t)128 * F_DIM;       // 2048*128 bf16 frag-packed
  u16* zcp   = Bpack + (size_t)O_DIM * 128;       // 8192*128 bf16 frag-packed
  float* out = (float*)d_out;

  prep_kernel<<<(128 * F_DIM) / 256, 256, 0, stream>>>(A, Bst, Apack, Bpack);
  k1_kernel<<<T_TOTAL / 16, 256, 0, stream>>>(x, protos, scales, Apack, zcp);
  k2_kernel<<<dim3(T_TOTAL / 16, 4), 256, 0, stream>>>(zcp, Bpack, out);
}

// Round 6
// 141.408 us; speedup vs baseline: 1.4065x; 1.3284x over previous
//
#include <hip/hip_runtime.h>
#include <hip/hip_bf16.h>

typedef unsigned short u16;
typedef __bf16 bf16x8 __attribute__((ext_vector_type(8)));
typedef float f32x4 __attribute__((ext_vector_type(4)));

#define T_TOTAL 8192
#define F_DIM   2048
#define E_NUM   8
#define ER_DIM  128
#define O_DIM   2048

__device__ __forceinline__ u16 f2bf(float f) {
  return __builtin_bit_cast(u16, (__bf16)f);  // RTNE
}
__device__ __forceinline__ unsigned pack2(float a, float b) {
  return (unsigned)f2bf(a) | ((unsigned)f2bf(b) << 16);
}
// async global->LDS, 16B per lane (dest must be wave-uniform-base + lane*16)
__device__ __forceinline__ void gld16(void* lds, const void* g) {
  __builtin_amdgcn_global_load_lds(
      (const __attribute__((address_space(1))) unsigned int*)g,
      (__attribute__((address_space(3))) unsigned int*)lds, 16, 0, 0);
}

// ---------------------------------------------------------------------------
// prep: A_stack [E,r,F] f32 -> Abf_sw [128][2048] bf16, XOR-swizzled per
//       128-elem K-chunk: Abf_sw[r][c] = A[r][c ^ ((r&7)<<3)]
//       B_stack [E,O,r] f32 -> BbfT_sw [2048 o][128 er] bf16, same swizzle.
// ---------------------------------------------------------------------------
__global__ __launch_bounds__(256) void prep_kernel(
    const float* __restrict__ A, const float* __restrict__ Bst,
    u16* __restrict__ Abf, u16* __restrict__ BbfT) {
  const int i = blockIdx.x * 256 + threadIdx.x;  // 0 .. 128*2048-1
  {
    const int r = i >> 11, c = i & 2047;
    Abf[i] = f2bf(A[r * F_DIM + (c ^ ((r & 7) << 3))]);
  }
  {
    const int o = i >> 7, ep = i & 127;
    const int er = ep ^ ((o & 7) << 3);
    const int e = er >> 4, j = er & 15;
    BbfT[i] = f2bf(Bst[e * (O_DIM * 16) + o * 16 + j]);
  }
}

// ---------------------------------------------------------------------------
// gemm1 (Round-3 proven): 32 tokens/block, 512 threads, 256 blocks.
// Double-buffered LDS, one barrier per K-step, DMA staging for A & protos,
// x via registers (fp32 sim + bf16 convert), swizzled linear LDS layouts.
// ---------------------------------------------------------------------------
__global__ __launch_bounds__(512, 2) void gemm1_kernel(
    const float* __restrict__ x, const float* __restrict__ protos,
    const float* __restrict__ scales, const u16* __restrict__ Abf,
    u16* __restrict__ zc) {
  __shared__ u16  as_[2][128 * 128];   // 64 KB  A tiles (swizzled content)
  __shared__ u16  xs [2][32 * 128];    // 16 KB  x tiles bf16 (swizzled)
  __shared__ float pk[2][8 * 128];     // 8 KB   proto chunks f32 (linear)
  __shared__ float sim_lds[32][8];
  __shared__ float w_lds[32][8];

  const int tid  = threadIdx.x;
  const int t0   = blockIdx.x * 32;
  const int row  = tid >> 4;          // 0..31 token
  const int seg  = tid & 15;          // 0..15 k-segment (8 floats each)
  const int lane = tid & 63;
  const int w    = tid >> 6;          // 0..7 wave -> er slice / expert
  const int g    = lane >> 4;
  const int lm   = lane & 15;

  float sacc[E_NUM];
#pragma unroll
  for (int e = 0; e < E_NUM; ++e) sacc[e] = 0.f;
  const f32x4 z4 = {0.f, 0.f, 0.f, 0.f};
  f32x4 acc[2];
  acc[0] = z4; acc[1] = z4;

  // ---- prologue: stage tile 0 ----
#pragma unroll
  for (int it = 0; it < 4; ++it) {
    const int c = it * 512 + tid;            // 16B chunk id, 0..2047
    const int r = c >> 4, ks = (c & 15) * 8;
    gld16(&as_[0][c * 8], Abf + (size_t)r * F_DIM + ks);
  }
  if (tid < 256)
    gld16(&pk[0][tid * 4], protos + (size_t)(tid >> 5) * F_DIM + (tid & 31) * 4);

  const float* xrow = x + (size_t)(t0 + row) * F_DIM + seg * 8;
  f32x4 xv0 = *reinterpret_cast<const f32x4*>(xrow);
  f32x4 xv1 = *reinterpret_cast<const f32x4*>(xrow + 4);
  {
    uint4 hv;
    hv.x = pack2(xv0[0], xv0[1]); hv.y = pack2(xv0[2], xv0[3]);
    hv.z = pack2(xv1[0], xv1[1]); hv.w = pack2(xv1[2], xv1[3]);
    *reinterpret_cast<uint4*>(
        &xs[0][row * 128 + ((seg * 8) ^ ((row & 7) << 3))]) = hv;
  }

  int buf = 0;
  for (int kt = 0; kt < F_DIM / 128; ++kt) {
    __syncthreads();   // tile kt fully staged (DMA drained + ds_writes)

    f32x4 xn0, xn1;
    if (kt < 15) {
      const int kb = (kt + 1) * 128;
      // issue next A tile DMA into buf^1
#pragma unroll
      for (int it = 0; it < 4; ++it) {
        const int c = it * 512 + tid;
        const int r = c >> 4, ks = (c & 15) * 8;
        gld16(&as_[buf ^ 1][c * 8], Abf + (size_t)r * F_DIM + kb + ks);
      }
      if (tid < 256)
        gld16(&pk[buf ^ 1][tid * 4],
              protos + (size_t)(tid >> 5) * F_DIM + kb + (tid & 31) * 4);
      // issue next x loads (regs)
      xn0 = *reinterpret_cast<const f32x4*>(xrow + kb);
      xn1 = *reinterpret_cast<const f32x4*>(xrow + kb + 4);
    }

    // ---- fp32 sim partials (current tile, register xv + LDS pk) ----
#pragma unroll
    for (int e = 0; e < E_NUM; ++e) {
      f32x4 p0 = *reinterpret_cast<const f32x4*>(&pk[buf][e * 128 + seg * 8]);
      f32x4 p1 = *reinterpret_cast<const f32x4*>(&pk[buf][e * 128 + seg * 8 + 4]);
      sacc[e] += xv0[0]*p0[0] + xv0[1]*p0[1] + xv0[2]*p0[2] + xv0[3]*p0[3]
               + xv1[0]*p1[0] + xv1[1]*p1[1] + xv1[2]*p1[2] + xv1[3]*p1[3];
    }

    // ---- MFMA: z-slice for er in [w*16, w*16+16) ----
#pragma unroll
    for (int kk = 0; kk < 4; ++kk) {
      const int cb = (kk * 32 + g * 8) ^ ((lm & 7) << 3);
      bf16x8 bv = *reinterpret_cast<const bf16x8*>(
          &as_[buf][(w * 16 + lm) * 128 + cb]);
#pragma unroll
      for (int m = 0; m < 2; ++m) {
        bf16x8 av = *reinterpret_cast<const bf16x8*>(
            &xs[buf][(m * 16 + lm) * 128 + cb]);
        acc[m] = __builtin_amdgcn_mfma_f32_16x16x32_bf16(av, bv, acc[m], 0, 0, 0);
      }
    }

    if (kt < 15) {
      uint4 hv;
      hv.x = pack2(xn0[0], xn0[1]); hv.y = pack2(xn0[2], xn0[3]);
      hv.z = pack2(xn1[0], xn1[1]); hv.w = pack2(xn1[2], xn1[3]);
      *reinterpret_cast<uint4*>(
          &xs[buf ^ 1][row * 128 + ((seg * 8) ^ ((row & 7) << 3))]) = hv;
      xv0 = xn0; xv1 = xn1;
    }
    buf ^= 1;
  }

  // ---- sim reduction over the 16 seg-lanes ----
#pragma unroll
  for (int s = 1; s < 16; s <<= 1)
#pragma unroll
    for (int e = 0; e < E_NUM; ++e) sacc[e] += __shfl_xor(sacc[e], s);
  if (seg < E_NUM) sim_lds[row][seg] = sacc[seg];
  __syncthreads();

  // ---- top-2 + softmax + scale ----
  if (tid < 32) {
    float sv[E_NUM];
#pragma unroll
    for (int e = 0; e < E_NUM; ++e) sv[e] = fabsf(sim_lds[tid][e]);
    int e0 = 0; float b0 = sv[0];
#pragma unroll
    for (int e = 1; e < E_NUM; ++e) if (sv[e] > b0) { b0 = sv[e]; e0 = e; }
    int e1 = -1; float b1 = -3.0e38f;
#pragma unroll
    for (int e = 0; e < E_NUM; ++e) if (e != e0 && sv[e] > b1) { b1 = sv[e]; e1 = e; }
    const float d  = __expf(b1 - b0);
    const float c0 = 1.f / (1.f + d);
    const float c1 = d * c0;
#pragma unroll
    for (int e = 0; e < E_NUM; ++e) w_lds[tid][e] = 0.f;
    w_lds[tid][e0] = c0 * scales[e0];
    w_lds[tid][e1] = c1 * scales[e1];
  }
  __syncthreads();

  // ---- epilogue: zc_sw[t][er ^ ((t&7)<<3)] = w[t][w] * z ----
#pragma unroll
  for (int m = 0; m < 2; ++m) {
#pragma unroll
    for (int i = 0; i < 4; ++i) {
      const int tl = m * 16 + g * 4 + i;
      const int er = w * 16 + lm;
      zc[(size_t)(t0 + tl) * ER_DIM + (er ^ ((tl & 7) << 3))] =
          f2bf(acc[m][i] * w_lds[tl][w]);
    }
  }
}

// ---------------------------------------------------------------------------
// gemm2: out[8192][2048] f32 = zc_sw @ BbfT_sw^T.
// 64x128 tile, K=128 one-shot, 48 KB LDS -> 3 blocks/CU, 2048 blocks.
// DMA staging, direct accumulator stores (64B quarter-wave segments).
// ---------------------------------------------------------------------------
__global__ __launch_bounds__(256, 3) void gemm2_kernel(
    const u16* __restrict__ zc, const u16* __restrict__ BbfT,
    float* __restrict__ out) {
  __shared__ u16 zcs[64 * 128];    // [64 t][128 er]   16 KB
  __shared__ u16 bbs[128 * 128];   // [128 o][128 er]  32 KB

  const int tid  = threadIdx.x;
  const int o0   = blockIdx.x * 128;
  const int t0   = blockIdx.y * 64;
  const int lane = tid & 63;
  const int w    = tid >> 6;
  const int wm   = w >> 1;         // token half (32)
  const int wn   = w & 1;          // o half (64)
  const int g    = lane >> 4, lm = lane & 15;

#pragma unroll
  for (int it = 0; it < 4; ++it) {
    const int c = it * 256 + tid;                  // 16B chunk, 0..1023
    gld16(&zcs[c * 8], zc + (size_t)t0 * ER_DIM + c * 8);
  }
#pragma unroll
  for (int it = 0; it < 8; ++it) {
    const int c = it * 256 + tid;                  // 16B chunk, 0..2047
    gld16(&bbs[c * 8], BbfT + (size_t)o0 * ER_DIM + c * 8);
  }
  __syncthreads();

  const f32x4 z4 = {0.f, 0.f, 0.f, 0.f};
  f32x4 acc[2][4];
#pragma unroll
  for (int m = 0; m < 2; ++m)
#pragma unroll
    for (int n = 0; n < 4; ++n) acc[m][n] = z4;

#pragma unroll
  for (int kk = 0; kk < 4; ++kk) {
    bf16x8 av[2], bv[4];
#pragma unroll
    for (int m = 0; m < 2; ++m) {
      const int tr = wm * 32 + m * 16 + lm;
      av[m] = *reinterpret_cast<const bf16x8*>(
          &zcs[tr * 128 + ((kk * 32 + g * 8) ^ ((tr & 7) << 3))]);
    }
#pragma unroll
    for (int n = 0; n < 4; ++n) {
      const int orow = wn * 64 + n * 16 + lm;
      bv[n] = *reinterpret_cast<const bf16x8*>(
          &bbs[orow * 128 + ((kk * 32 + g * 8) ^ ((orow & 7) << 3))]);
    }
#pragma unroll
    for (int m = 0; m < 2; ++m)
#pragma unroll
      for (int n = 0; n < 4; ++n)
        acc[m][n] = __builtin_amdgcn_mfma_f32_16x16x32_bf16(av[m], bv[n],
                                                            acc[m][n], 0, 0, 0);
  }

  // direct stores: per (m,n,i) one f32; 16-lane group = 64B contiguous
#pragma unroll
  for (int m = 0; m < 2; ++m) {
#pragma unroll
    for (int n = 0; n < 4; ++n) {
      const int o = o0 + wn * 64 + n * 16 + lm;
#pragma unroll
      for (int i = 0; i < 4; ++i) {
        const int t = t0 + wm * 32 + m * 16 + g * 4 + i;
        out[(size_t)t * O_DIM + o] = acc[m][n][i];
      }
    }
  }
}

// ---------------------------------------------------------------------------
extern "C" void kernel_launch(void* const* d_in, const int* in_sizes, int n_in,
                              void* d_out, int out_size, void* d_ws, size_t ws_size,
                              hipStream_t stream) {
  const float* x      = (const float*)d_in[0];
  const float* protos = (const float*)d_in[1];
  const float* A      = (const float*)d_in[2];
  const float* Bst    = (const float*)d_in[3];
  const float* scales = (const float*)d_in[4];
  // d_in[5] = top_k (always 2)

  u16* zcw  = (u16*)d_ws;                              // 8192*128 bf16 (swizzled)
  u16* Abf  = zcw + (size_t)T_TOTAL * ER_DIM;          // 128*2048 bf16 (swizzled)
  u16* BbfT = Abf + (size_t)ER_DIM * F_DIM;            // 2048*128 bf16 (swizzled)
  float* out = (float*)d_out;

  prep_kernel<<<(ER_DIM * F_DIM) / 256, 256, 0, stream>>>(A, Bst, Abf, BbfT);
  gemm1_kernel<<<T_TOTAL / 32, 512, 0, stream>>>(x, protos, scales, Abf, zcw);
  gemm2_kernel<<<dim3(O_DIM / 128, T_TOTAL / 64), 256, 0, stream>>>(zcw, BbfT, out);
}